// Round 5
// baseline (125.709 us; speedup 1.0000x reference)
//
#include <hip/hip_runtime.h>

#define K_HP 0.0244f
#define I_THRESH 0.39063f

typedef float f32x4 __attribute__((ext_vector_type(4)));  // native vector: nontemporal-builtin-compatible

// tanh(v) = 1 - 2/(1+exp(2v)); NaN-free at both extremes.
__device__ __forceinline__ float tanh_fast(float v) {
    float e = __expf(2.0f * v);                       // v_exp_f32 path
    float r = __builtin_amdgcn_rcpf(1.0f + e);        // v_rcp_f32, ~1 ulp
    return fmaf(-2.0f, r, 1.0f);
}

struct Weights {
    float W1[8], B1[8], W2[64], B2[8], W3[8], B3;
};

__device__ __forceinline__ float row_compute(float hi, float aim, float rate,
                                             float lst, const Weights& w) {
    const float a   = 0.3417968f;   // interior PID_KP value
    const float Kic = 0.1503906f;   // PID_KI is constant everywhere

    float d_raw = aim - hi;
    float diff  = d_raw * K_HP;

    float h1[8];
    #pragma unroll
    for (int j = 0; j < 8; ++j) h1[j] = tanh_fast(fmaf(diff, w.W1[j], w.B1[j]));
    float k_out = w.B3;
    #pragma unroll
    for (int j = 0; j < 8; ++j) {
        float acc = w.B2[j];
        #pragma unroll
        for (int k = 0; k < 8; ++k) acc = fmaf(h1[k], w.W2[k * 8 + j], acc);
        k_out = fmaf(tanh_fast(acc), w.W3[j], k_out);
    }
    float diff_real = d_raw * k_out;

    float ad = fabsf(diff);
    float t  = fminf(fmaxf((ad - 2.5f) * (1.0f / 7.5f), 0.0f), 1.0f);
    float Kp = fmaf(t, 0.5f - a, a) * rate;
    float Ki = Kic * rate;

    float ivalue = (ad < I_THRESH) ? 0.0f : diff_real * 0.5f;
    return lst + fmaf(Ki, ivalue, Kp * diff_real);
}

// Each thread owns 4 consecutive rows = 208 B = 13 aligned float4 loads.
// Every byte of x fetched exactly once, full 16B/lane utilization, no LDS,
// no barriers. last/out for the 4 rows are one float4 each.
__global__ __launch_bounds__(256) void pid_kernel(
    const float* __restrict__ x,
    const float* __restrict__ last,
    const float* __restrict__ w1, const float* __restrict__ b1,
    const float* __restrict__ w2, const float* __restrict__ b2,
    const float* __restrict__ w3, const float* __restrict__ b3,
    float* __restrict__ out, int n)
{
    // Wave-uniform weight loads -> scalar (s_load) registers.
    Weights w;
    #pragma unroll
    for (int j = 0; j < 8; ++j) { w.W1[j] = w1[j]; w.B1[j] = b1[j]; w.B2[j] = b2[j]; w.W3[j] = w3[j]; }
    #pragma unroll
    for (int j = 0; j < 64; ++j) w.W2[j] = w2[j];
    w.B3 = b3[0];

    const int tid     = blockIdx.x * blockDim.x + threadIdx.x;
    const int stride  = gridDim.x * blockDim.x;
    const int ngroups = n >> 2;                 // groups of 4 rows

    for (int g = tid; g < ngroups; g += stride) {
        const f32x4* src = (const f32x4*)x + (size_t)g * 13;
        f32x4 c[13];
        #pragma unroll
        for (int k = 0; k < 13; ++k) c[k] = __builtin_nontemporal_load(&src[k]);
        f32x4 lst = __builtin_nontemporal_load((const f32x4*)last + g);

        // row r needs dwords 13r+5, 13r+7, 13r+11 (hi, aim, rate)
        f32x4 res;
        res.x = row_compute(c[1].y,  c[1].w,  c[2].w,  lst.x, w);  // d5,  d7,  d11
        res.y = row_compute(c[4].z,  c[5].x,  c[6].x,  lst.y, w);  // d18, d20, d24
        res.z = row_compute(c[7].w,  c[8].y,  c[9].y,  lst.z, w);  // d31, d33, d37
        res.w = row_compute(c[11].x, c[11].z, c[12].z, lst.w, w);  // d44, d46, d50

        __builtin_nontemporal_store(res, (f32x4*)out + g);
    }

    // Tail rows (n % 4) — not taken for n = 4194304, kept for generality.
    const int tailStart = ngroups << 2;
    for (int i = tailStart + tid; i < n; i += stride) {
        const float* row = x + (size_t)i * 13;
        out[i] = row_compute(row[5], row[7], row[11], last[i], w);
    }
}

extern "C" void kernel_launch(void* const* d_in, const int* in_sizes, int n_in,
                              void* d_out, int out_size, void* d_ws, size_t ws_size,
                              hipStream_t stream) {
    const float* x    = (const float*)d_in[0];
    const float* last = (const float*)d_in[1];
    const float* w1   = (const float*)d_in[2];
    const float* b1   = (const float*)d_in[3];
    const float* w2   = (const float*)d_in[4];
    const float* b2   = (const float*)d_in[5];
    const float* w3   = (const float*)d_in[6];
    const float* b3   = (const float*)d_in[7];
    float* out = (float*)d_out;
    int n = out_size;
    pid_kernel<<<2048, 256, 0, stream>>>(x, last, w1, b1, w2, b2, w3, b3, out, n);
}

// Round 6
// 49.382 us; speedup vs baseline: 2.5456x; 2.5456x over previous
//
#include <hip/hip_runtime.h>

#define K_HP 0.0244f
#define I_THRESH 0.39063f

typedef float f32x4 __attribute__((ext_vector_type(4)));

// tanh(v) = 1 - 2/(1+exp(2v)); NaN-free at both extremes.
__device__ __forceinline__ float tanh_fast(float v) {
    float e = __expf(2.0f * v);                       // v_exp_f32 path
    float r = __builtin_amdgcn_rcpf(1.0f + e);        // v_rcp_f32, ~1 ulp
    return fmaf(-2.0f, r, 1.0f);
}

struct Weights {
    float W1[8], B1[8], W2[64], B2[8], W3[8], B3;
};

__device__ __forceinline__ float row_compute(float hi, float aim, float rate,
                                             float lst, const Weights& w) {
    const float a   = 0.3417968f;   // interior PID_KP value
    const float Kic = 0.1503906f;   // PID_KI is constant everywhere

    float d_raw = aim - hi;
    float diff  = d_raw * K_HP;

    float h1[8];
    #pragma unroll
    for (int j = 0; j < 8; ++j) h1[j] = tanh_fast(fmaf(diff, w.W1[j], w.B1[j]));
    float k_out = w.B3;
    #pragma unroll
    for (int j = 0; j < 8; ++j) {
        float acc = w.B2[j];
        #pragma unroll
        for (int k = 0; k < 8; ++k) acc = fmaf(h1[k], w.W2[k * 8 + j], acc);
        k_out = fmaf(tanh_fast(acc), w.W3[j], k_out);
    }
    float diff_real = d_raw * k_out;

    float ad = fabsf(diff);
    float t  = fminf(fmaxf((ad - 2.5f) * (1.0f / 7.5f), 0.0f), 1.0f);
    float Kp = fmaf(t, 0.5f - a, a) * rate;
    float Ki = Kic * rate;

    float ivalue = (ad < I_THRESH) ? 0.0f : diff_real * 0.5f;
    return lst + fmaf(Ki, ivalue, Kp * diff_real);
}

constexpr int ROWS    = 256;              // rows per tile = threads per block
constexpr int TILE_F4 = ROWS * 13 / 4;    // 832 float4 chunks = 13312 B per tile

// Double-buffered LDS staging: coalesced float4 loads of tile k+1 issued
// BEFORE the compute of tile k (MLP hides HBM latency), ds_write after,
// one barrier per tile. Buffers alternate so writes never collide with the
// current tile's reads.
__global__ __launch_bounds__(256) void pid_kernel(
    const float* __restrict__ x,
    const float* __restrict__ last,
    const float* __restrict__ w1, const float* __restrict__ b1,
    const float* __restrict__ w2, const float* __restrict__ b2,
    const float* __restrict__ w3, const float* __restrict__ b3,
    float* __restrict__ out, int n)
{
    __shared__ f32x4 lds4[2][TILE_F4];

    // Wave-uniform weight loads -> scalar registers, hoisted out of the loop.
    Weights w;
    #pragma unroll
    for (int j = 0; j < 8; ++j) { w.W1[j] = w1[j]; w.B1[j] = b1[j]; w.B2[j] = b2[j]; w.W3[j] = w3[j]; }
    #pragma unroll
    for (int j = 0; j < 64; ++j) w.W2[j] = w2[j];
    w.B3 = b3[0];

    const int t          = threadIdx.x;
    const int nFull      = n / ROWS;          // full tiles
    const int tileStride = gridDim.x;
    int tile = blockIdx.x;

    if (tile < nFull) {
        // Prologue: stage tile -> buf 0 (coalesced: lane i reads chunk base+i)
        const f32x4* src = (const f32x4*)x + (size_t)tile * TILE_F4;
        lds4[0][t]       = src[t];
        lds4[0][t + 256] = src[t + 256];
        lds4[0][t + 512] = src[t + 512];
        if (t < TILE_F4 - 768) lds4[0][t + 768] = src[t + 768];
        __syncthreads();
    }

    int buf = 0;
    while (tile < nFull) {
        const int  next     = tile + tileStride;
        const bool haveNext = next < nFull;

        // (1) issue next tile's coalesced loads into registers
        f32x4 a0 = {}, a1 = {}, a2 = {}, a3 = {};
        if (haveNext) {
            const f32x4* src = (const f32x4*)x + (size_t)next * TILE_F4;
            a0 = src[t];
            a1 = src[t + 256];
            a2 = src[t + 512];
            if (t < TILE_F4 - 768) a3 = src[t + 768];
        }

        // (2) compute current tile from LDS (stride-13 -> 2-way bank alias, free)
        const float* L = (const float*)lds4[buf];
        const int i = tile * ROWS + t;
        out[i] = row_compute(L[t * 13 + 5], L[t * 13 + 7], L[t * 13 + 11],
                             last[i], w);

        // (3) stage next tile into the OTHER buffer (prev readers of it
        //     finished before the previous barrier)
        if (haveNext) {
            lds4[buf ^ 1][t]       = a0;
            lds4[buf ^ 1][t + 256] = a1;
            lds4[buf ^ 1][t + 512] = a2;
            if (t < TILE_F4 - 768) lds4[buf ^ 1][t + 768] = a3;
        }
        __syncthreads();   // writes visible; orders this tile's reads before next overwrite
        buf ^= 1;
        tile = next;
    }

    // Tail rows (n % 256) — not taken for n = 4194304, kept for generality.
    const int tailStart = nFull * ROWS;
    for (int i = tailStart + blockIdx.x * blockDim.x + t; i < n;
         i += gridDim.x * blockDim.x) {
        const float* row = x + (size_t)i * 13;
        out[i] = row_compute(row[5], row[7], row[11], last[i], w);
    }
}

extern "C" void kernel_launch(void* const* d_in, const int* in_sizes, int n_in,
                              void* d_out, int out_size, void* d_ws, size_t ws_size,
                              hipStream_t stream) {
    const float* x    = (const float*)d_in[0];
    const float* last = (const float*)d_in[1];
    const float* w1   = (const float*)d_in[2];
    const float* b1   = (const float*)d_in[3];
    const float* w2   = (const float*)d_in[4];
    const float* b2   = (const float*)d_in[5];
    const float* w3   = (const float*)d_in[6];
    const float* b3   = (const float*)d_in[7];
    float* out = (float*)d_out;
    int n = out_size;
    pid_kernel<<<2048, 256, 0, stream>>>(x, last, w1, b1, w2, b2, w3, b3, out, n);
}

// Round 7
// 47.092 us; speedup vs baseline: 2.6694x; 1.0486x over previous
//
#include <hip/hip_runtime.h>

#define K_HP 0.0244f
#define I_THRESH 0.39063f

// 12B vector, 4B-aligned: loads cols 5..7 in one global_load_dwordx3.
typedef float f32x3 __attribute__((ext_vector_type(3), aligned(4)));

// tanh(v) = 1 - 2/(1+exp(2v)); NaN-free at both extremes.
__device__ __forceinline__ float tanh_fast(float v) {
    float e = __expf(2.0f * v);                       // v_exp_f32 path
    float r = __builtin_amdgcn_rcpf(1.0f + e);        // v_rcp_f32, ~1 ulp
    return fmaf(-2.0f, r, 1.0f);
}

struct Weights {
    float W1[8], B1[8], W2[64], B2[8], W3[8], B3;
};

__device__ __forceinline__ float row_compute(float hi, float aim, float rate,
                                             float lst, const Weights& w) {
    const float a   = 0.3417968f;   // interior PID_KP value
    const float Kic = 0.1503906f;   // PID_KI is constant everywhere

    float d_raw = aim - hi;
    float diff  = d_raw * K_HP;

    float h1[8];
    #pragma unroll
    for (int j = 0; j < 8; ++j) h1[j] = tanh_fast(fmaf(diff, w.W1[j], w.B1[j]));
    float k_out = w.B3;
    #pragma unroll
    for (int j = 0; j < 8; ++j) {
        float acc = w.B2[j];
        #pragma unroll
        for (int k = 0; k < 8; ++k) acc = fmaf(h1[k], w.W2[k * 8 + j], acc);
        k_out = fmaf(tanh_fast(acc), w.W3[j], k_out);
    }
    float diff_real = d_raw * k_out;

    float ad = fabsf(diff);
    float t  = fminf(fmaxf((ad - 2.5f) * (1.0f / 7.5f), 0.0f), 1.0f);
    float Kp = fmaf(t, 0.5f - a, a) * rate;
    float Ki = Kic * rate;

    float ivalue = (ad < I_THRESH) ? 0.0f : diff_real * 0.5f;
    return lst + fmaf(Ki, ivalue, Kp * diff_real);
}

__global__ __launch_bounds__(256) void pid_kernel(
    const float* __restrict__ x,
    const float* __restrict__ last,
    const float* __restrict__ w1, const float* __restrict__ b1,
    const float* __restrict__ w2, const float* __restrict__ b2,
    const float* __restrict__ w3, const float* __restrict__ b3,
    float* __restrict__ out, int n)
{
    // Wave-uniform weight loads -> scalar registers, hoisted out of the loop.
    Weights w;
    #pragma unroll
    for (int j = 0; j < 8; ++j) { w.W1[j] = w1[j]; w.B1[j] = b1[j]; w.B2[j] = b2[j]; w.W3[j] = w3[j]; }
    #pragma unroll
    for (int j = 0; j < 64; ++j) w.W2[j] = w2[j];
    w.B3 = b3[0];

    const int tid    = blockIdx.x * blockDim.x + threadIdx.x;
    const int stride = gridDim.x * blockDim.x;

    for (int i = tid; i < n; i += stride) {
        const float* row = x + (size_t)i * 13;
        // One dwordx3 covers cols 5..7 (hi, _, aim): 2 VMEM requests/row not 3.
        f32x3 har  = *(const f32x3*)(row + 5);
        float rate = row[11];
        out[i] = row_compute(har.x, har.z, rate, last[i], w);
    }
}

extern "C" void kernel_launch(void* const* d_in, const int* in_sizes, int n_in,
                              void* d_out, int out_size, void* d_ws, size_t ws_size,
                              hipStream_t stream) {
    const float* x    = (const float*)d_in[0];
    const float* last = (const float*)d_in[1];
    const float* w1   = (const float*)d_in[2];
    const float* b1   = (const float*)d_in[3];
    const float* w2   = (const float*)d_in[4];
    const float* b2   = (const float*)d_in[5];
    const float* w3   = (const float*)d_in[6];
    const float* b3   = (const float*)d_in[7];
    float* out = (float*)d_out;
    int n = out_size;
    pid_kernel<<<2048, 256, 0, stream>>>(x, last, w1, b1, w2, b2, w3, b3, out, n);
}